// Round 1
// baseline (621.172 us; speedup 1.0000x reference)
//
#include <hip/hip_runtime.h>
#include <stdint.h>

// QLoRA linear: out = x @ (scale*qweight^T + A@B) + bias
// M=8192 (B*S), N=4096 (D_OUT), K=4096 (D_IN), RANK=16
//
// Strategy: fold LoRA + dequant into one bf16 weight matrix W_eff[n][k]
// (B^T layout), convert x to bf16, then one m97-style 128x128 MFMA GEMM.

static constexpr int Mdim = 8192;
static constexpr int Ndim = 4096;
static constexpr int Kdim = 4096;
static constexpr int RANK = 16;

typedef __bf16 bf16x8 __attribute__((ext_vector_type(8)));
typedef float f32x4 __attribute__((ext_vector_type(4)));

__device__ __forceinline__ void async_copy16(const void* gptr, void* lptr) {
    auto g = (const __attribute__((address_space(1))) unsigned char*)(uintptr_t)gptr;
    auto l = (__attribute__((address_space(3))) unsigned char*)(uintptr_t)lptr;
    __builtin_amdgcn_global_load_lds(g, l, 16, 0, 0);
}

// ---------------- x fp32 -> bf16 ----------------
__global__ void __launch_bounds__(256) convert_x_kernel(const float* __restrict__ x,
                                                        __bf16* __restrict__ xb) {
    size_t i = ((size_t)blockIdx.x * 256 + threadIdx.x) * 8;
    const float4* p = (const float4*)(x + i);
    float4 v0 = p[0], v1 = p[1];
    bf16x8 o;
    o[0] = (__bf16)v0.x; o[1] = (__bf16)v0.y; o[2] = (__bf16)v0.z; o[3] = (__bf16)v0.w;
    o[4] = (__bf16)v1.x; o[5] = (__bf16)v1.y; o[6] = (__bf16)v1.z; o[7] = (__bf16)v1.w;
    *(bf16x8*)(xb + i) = o;
}

// ---------------- W_eff = scale*qw + (A@B)^T, bf16 [N][K] ----------------
// Each thread: 4 consecutive n, 8 consecutive k.
__global__ void __launch_bounds__(256) prep_w_kernel(const int* __restrict__ qw,
                                                     const float* __restrict__ scales,
                                                     const float* __restrict__ lA,   // [K][RANK]
                                                     const float* __restrict__ lB,   // [RANK][N]
                                                     __bf16* __restrict__ weff) {
    int t = blockIdx.x * 256 + threadIdx.x;
    int kg = t & 511;           // Kdim/8 = 512 k-groups
    int n4 = t >> 9;            // 0..1023
    int k0 = kg << 3;
    int n0 = n4 << 2;
    float s = scales[0];

    float bcol[4][RANK];
#pragma unroll
    for (int nn = 0; nn < 4; ++nn)
#pragma unroll
        for (int r = 0; r < RANK; ++r)
            bcol[nn][r] = lB[(size_t)r * Ndim + n0 + nn];

    float oacc[4][8];
#pragma unroll
    for (int nn = 0; nn < 4; ++nn) {
        const int4* q = (const int4*)(qw + (size_t)(n0 + nn) * Kdim + k0);
        int4 qa = q[0], qb = q[1];
        oacc[nn][0] = qa.x * s; oacc[nn][1] = qa.y * s;
        oacc[nn][2] = qa.z * s; oacc[nn][3] = qa.w * s;
        oacc[nn][4] = qb.x * s; oacc[nn][5] = qb.y * s;
        oacc[nn][6] = qb.z * s; oacc[nn][7] = qb.w * s;
    }

#pragma unroll
    for (int kk = 0; kk < 8; ++kk) {
        const float4* ap = (const float4*)(lA + (size_t)(k0 + kk) * RANK);
        float4 a0 = ap[0], a1 = ap[1], a2 = ap[2], a3 = ap[3];
        float av[RANK] = {a0.x, a0.y, a0.z, a0.w, a1.x, a1.y, a1.z, a1.w,
                          a2.x, a2.y, a2.z, a2.w, a3.x, a3.y, a3.z, a3.w};
#pragma unroll
        for (int nn = 0; nn < 4; ++nn) {
            float d = 0.f;
#pragma unroll
            for (int r = 0; r < RANK; ++r) d += av[r] * bcol[nn][r];
            oacc[nn][kk] += d;
        }
    }

#pragma unroll
    for (int nn = 0; nn < 4; ++nn) {
        bf16x8 o;
#pragma unroll
        for (int kk = 0; kk < 8; ++kk) o[kk] = (__bf16)oacc[nn][kk];
        *(bf16x8*)(weff + (size_t)(n0 + nn) * Kdim + k0) = o;
    }
}

// ---------------- main GEMM: C[m][n] = A[m][:] . Bt[n][:] + bias[n] ----------------
// 128x128 block tile, 256 threads = 4 waves, each wave 64x64 (4x4 MFMA 16x16x32).
__global__ void __launch_bounds__(256) gemm_kernel(const __bf16* __restrict__ A,   // [M][K]
                                                   const __bf16* __restrict__ Bt,  // [N][K]
                                                   const float* __restrict__ bias, // [N]
                                                   float* __restrict__ C) {        // [M][N]
    __shared__ __align__(16) __bf16 sA[128 * 32];
    __shared__ __align__(16) __bf16 sB[128 * 32];

    const int tid = threadIdx.x;
    const int wave = tid >> 6, lane = tid & 63;
    const int wm = wave >> 1, wn = wave & 1;
    const int quad = lane >> 4, l16 = lane & 15;
    const int bm = blockIdx.y, bn = blockIdx.x;

    // staging: thread t covers row (t>>2) of a 64-row half-tile, bytes (t&3)*16
    const int arow = tid >> 2;
    const int acolb = (tid & 3) * 16;
    const size_t a_base = (size_t)(bm * 128 + arow) * Kdim;
    const size_t b_base = (size_t)(bn * 128 + arow) * Kdim;

    f32x4 acc[4][4] = {};

    for (int k0 = 0; k0 < Kdim; k0 += 32) {
        __syncthreads();
        async_copy16((const char*)(A + a_base + k0) + acolb,             (char*)sA + tid * 16);
        async_copy16((const char*)(A + a_base + (size_t)64 * Kdim + k0) + acolb, (char*)sA + 4096 + tid * 16);
        async_copy16((const char*)(Bt + b_base + k0) + acolb,            (char*)sB + tid * 16);
        async_copy16((const char*)(Bt + b_base + (size_t)64 * Kdim + k0) + acolb, (char*)sB + 4096 + tid * 16);
        __syncthreads();

        bf16x8 aF[4], bF[4];
#pragma unroll
        for (int i = 0; i < 4; ++i)
            aF[i] = *(const bf16x8*)(sA + (wm * 64 + i * 16 + l16) * 32 + quad * 8);
#pragma unroll
        for (int j = 0; j < 4; ++j)
            bF[j] = *(const bf16x8*)(sB + (wn * 64 + j * 16 + l16) * 32 + quad * 8);

#pragma unroll
        for (int i = 0; i < 4; ++i)
#pragma unroll
            for (int j = 0; j < 4; ++j)
                acc[i][j] = __builtin_amdgcn_mfma_f32_16x16x32_bf16(aF[i], bF[j], acc[i][j], 0, 0, 0);
    }

    // epilogue: C/D layout col=lane&15, row=quad*4+reg
    const int col0 = bn * 128 + wn * 64 + l16;
    const int row0 = bm * 128 + wm * 64 + quad * 4;
#pragma unroll
    for (int j = 0; j < 4; ++j) {
        const int col = col0 + j * 16;
        const float bj = bias[col];
#pragma unroll
        for (int i = 0; i < 4; ++i) {
            const int r0 = row0 + i * 16;
#pragma unroll
            for (int r = 0; r < 4; ++r)
                C[(size_t)(r0 + r) * Ndim + col] = acc[i][j][r] + bj;
        }
    }
}

extern "C" void kernel_launch(void* const* d_in, const int* in_sizes, int n_in,
                              void* d_out, int out_size, void* d_ws, size_t ws_size,
                              hipStream_t stream) {
    const float* x      = (const float*)d_in[0];
    const int*   qw     = (const int*)d_in[1];
    const float* scales = (const float*)d_in[2];
    const float* bias   = (const float*)d_in[3];
    const float* lA     = (const float*)d_in[4];
    const float* lB     = (const float*)d_in[5];
    float* out = (float*)d_out;

    __bf16* xb   = (__bf16*)d_ws;                                   // 64 MiB
    __bf16* weff = (__bf16*)((char*)d_ws + (size_t)Mdim * Kdim * 2); // +32 MiB

    convert_x_kernel<<<Mdim * Kdim / (256 * 8), 256, 0, stream>>>(x, xb);
    prep_w_kernel<<<(Ndim / 4) * (Kdim / 8) / 256, 256, 0, stream>>>(qw, scales, lA, lB, weff);
    dim3 grid(Ndim / 128, Mdim / 128);
    gemm_kernel<<<grid, 256, 0, stream>>>(xb, weff, bias, out);
}

// Round 2
// 614.101 us; speedup vs baseline: 1.0115x; 1.0115x over previous
//
#include <hip/hip_runtime.h>
#include <stdint.h>

// QLoRA linear: out = x @ (scale*qweight^T + A@B) + bias
// M=8192 (B*S), N=4096 (D_OUT), K=4096 (D_IN), RANK=16
//
// R2: fuse convert_x + prep_w into one kernel (role split by blockIdx) so the
// two memory-bound prep passes overlap instead of serializing. GEMM unchanged.

static constexpr int Mdim = 8192;
static constexpr int Ndim = 4096;
static constexpr int Kdim = 4096;
static constexpr int RANK = 16;

static constexpr int CONV_BLOCKS = Mdim * Kdim / (256 * 8);          // 16384
static constexpr int PREP_BLOCKS = (Ndim / 4) * (Kdim / 8) / 256;    // 2048

typedef __bf16 bf16x8 __attribute__((ext_vector_type(8)));
typedef float f32x4 __attribute__((ext_vector_type(4)));

__device__ __forceinline__ void async_copy16(const void* gptr, void* lptr) {
    auto g = (const __attribute__((address_space(1))) unsigned char*)(uintptr_t)gptr;
    auto l = (__attribute__((address_space(3))) unsigned char*)(uintptr_t)lptr;
    __builtin_amdgcn_global_load_lds(g, l, 16, 0, 0);
}

// ---------------- fused prep: x fp32->bf16  +  W_eff build ----------------
__global__ void __launch_bounds__(256) fused_prep_kernel(
        const float* __restrict__ x,
        const int* __restrict__ qw,
        const float* __restrict__ scales,
        const float* __restrict__ lA,   // [K][RANK]
        const float* __restrict__ lB,   // [RANK][N]
        __bf16* __restrict__ xb,
        __bf16* __restrict__ weff) {
    if (blockIdx.x < CONV_BLOCKS) {
        // -------- role A: x fp32 -> bf16, 8 elems/thread --------
        size_t i = ((size_t)blockIdx.x * 256 + threadIdx.x) * 8;
        const float4* p = (const float4*)(x + i);
        float4 v0 = p[0], v1 = p[1];
        bf16x8 o;
        o[0] = (__bf16)v0.x; o[1] = (__bf16)v0.y; o[2] = (__bf16)v0.z; o[3] = (__bf16)v0.w;
        o[4] = (__bf16)v1.x; o[5] = (__bf16)v1.y; o[6] = (__bf16)v1.z; o[7] = (__bf16)v1.w;
        *(bf16x8*)(xb + i) = o;
        return;
    }
    // -------- role B: W_eff = scale*qw + (A@B)^T, bf16 [N][K] --------
    int t = (blockIdx.x - CONV_BLOCKS) * 256 + threadIdx.x;
    int kg = t & 511;           // Kdim/8 = 512 k-groups
    int n4 = t >> 9;            // 0..1023
    int k0 = kg << 3;
    int n0 = n4 << 2;
    float s = scales[0];

    float bcol[4][RANK];
#pragma unroll
    for (int nn = 0; nn < 4; ++nn)
#pragma unroll
        for (int r = 0; r < RANK; ++r)
            bcol[nn][r] = lB[(size_t)r * Ndim + n0 + nn];

    float oacc[4][8];
#pragma unroll
    for (int nn = 0; nn < 4; ++nn) {
        const int4* q = (const int4*)(qw + (size_t)(n0 + nn) * Kdim + k0);
        int4 qa = q[0], qb = q[1];
        oacc[nn][0] = qa.x * s; oacc[nn][1] = qa.y * s;
        oacc[nn][2] = qa.z * s; oacc[nn][3] = qa.w * s;
        oacc[nn][4] = qb.x * s; oacc[nn][5] = qb.y * s;
        oacc[nn][6] = qb.z * s; oacc[nn][7] = qb.w * s;
    }

#pragma unroll
    for (int kk = 0; kk < 8; ++kk) {
        const float4* ap = (const float4*)(lA + (size_t)(k0 + kk) * RANK);
        float4 a0 = ap[0], a1 = ap[1], a2 = ap[2], a3 = ap[3];
        float av[RANK] = {a0.x, a0.y, a0.z, a0.w, a1.x, a1.y, a1.z, a1.w,
                          a2.x, a2.y, a2.z, a2.w, a3.x, a3.y, a3.z, a3.w};
#pragma unroll
        for (int nn = 0; nn < 4; ++nn) {
            float d = 0.f;
#pragma unroll
            for (int r = 0; r < RANK; ++r) d += av[r] * bcol[nn][r];
            oacc[nn][kk] += d;
        }
    }

#pragma unroll
    for (int nn = 0; nn < 4; ++nn) {
        bf16x8 o;
#pragma unroll
        for (int kk = 0; kk < 8; ++kk) o[kk] = (__bf16)oacc[nn][kk];
        *(bf16x8*)(weff + (size_t)(n0 + nn) * Kdim + k0) = o;
    }
}

// ---------------- main GEMM: C[m][n] = A[m][:] . Bt[n][:] + bias[n] ----------------
// 128x128 block tile, 256 threads = 4 waves, each wave 64x64 (4x4 MFMA 16x16x32).
__global__ void __launch_bounds__(256) gemm_kernel(const __bf16* __restrict__ A,   // [M][K]
                                                   const __bf16* __restrict__ Bt,  // [N][K]
                                                   const float* __restrict__ bias, // [N]
                                                   float* __restrict__ C) {        // [M][N]
    __shared__ __align__(16) __bf16 sA[128 * 32];
    __shared__ __align__(16) __bf16 sB[128 * 32];

    const int tid = threadIdx.x;
    const int wave = tid >> 6, lane = tid & 63;
    const int wm = wave >> 1, wn = wave & 1;
    const int quad = lane >> 4, l16 = lane & 15;
    const int bm = blockIdx.y, bn = blockIdx.x;

    const int arow = tid >> 2;
    const int acolb = (tid & 3) * 16;
    const size_t a_base = (size_t)(bm * 128 + arow) * Kdim;
    const size_t b_base = (size_t)(bn * 128 + arow) * Kdim;

    f32x4 acc[4][4] = {};

    for (int k0 = 0; k0 < Kdim; k0 += 32) {
        __syncthreads();
        async_copy16((const char*)(A + a_base + k0) + acolb,             (char*)sA + tid * 16);
        async_copy16((const char*)(A + a_base + (size_t)64 * Kdim + k0) + acolb, (char*)sA + 4096 + tid * 16);
        async_copy16((const char*)(Bt + b_base + k0) + acolb,            (char*)sB + tid * 16);
        async_copy16((const char*)(Bt + b_base + (size_t)64 * Kdim + k0) + acolb, (char*)sB + 4096 + tid * 16);
        __syncthreads();

        bf16x8 aF[4], bF[4];
#pragma unroll
        for (int i = 0; i < 4; ++i)
            aF[i] = *(const bf16x8*)(sA + (wm * 64 + i * 16 + l16) * 32 + quad * 8);
#pragma unroll
        for (int j = 0; j < 4; ++j)
            bF[j] = *(const bf16x8*)(sB + (wn * 64 + j * 16 + l16) * 32 + quad * 8);

#pragma unroll
        for (int i = 0; i < 4; ++i)
#pragma unroll
            for (int j = 0; j < 4; ++j)
                acc[i][j] = __builtin_amdgcn_mfma_f32_16x16x32_bf16(aF[i], bF[j], acc[i][j], 0, 0, 0);
    }

    // epilogue: C/D layout col=lane&15, row=quad*4+reg
    const int col0 = bn * 128 + wn * 64 + l16;
    const int row0 = bm * 128 + wm * 64 + quad * 4;
#pragma unroll
    for (int j = 0; j < 4; ++j) {
        const int col = col0 + j * 16;
        const float bj = bias[col];
#pragma unroll
        for (int i = 0; i < 4; ++i) {
            const int r0 = row0 + i * 16;
#pragma unroll
            for (int r = 0; r < 4; ++r)
                C[(size_t)(r0 + r) * Ndim + col] = acc[i][j][r] + bj;
        }
    }
}

extern "C" void kernel_launch(void* const* d_in, const int* in_sizes, int n_in,
                              void* d_out, int out_size, void* d_ws, size_t ws_size,
                              hipStream_t stream) {
    const float* x      = (const float*)d_in[0];
    const int*   qw     = (const int*)d_in[1];
    const float* scales = (const float*)d_in[2];
    const float* bias   = (const float*)d_in[3];
    const float* lA     = (const float*)d_in[4];
    const float* lB     = (const float*)d_in[5];
    float* out = (float*)d_out;

    __bf16* xb   = (__bf16*)d_ws;                                    // 64 MiB
    __bf16* weff = (__bf16*)((char*)d_ws + (size_t)Mdim * Kdim * 2); // +32 MiB

    fused_prep_kernel<<<CONV_BLOCKS + PREP_BLOCKS, 256, 0, stream>>>(
        x, qw, scales, lA, lB, xb, weff);
    dim3 grid(Ndim / 128, Mdim / 128);
    gemm_kernel<<<grid, 256, 0, stream>>>(xb, weff, bias, out);
}

// Round 3
// 474.297 us; speedup vs baseline: 1.3097x; 1.2948x over previous
//
#include <hip/hip_runtime.h>
#include <stdint.h>
#include <math.h>

// QLoRA linear: out = x @ (scale*qweight^T) + bias + (x@A)@B
// M=8192, N=4096, K=4096, RANK=16.
//
// R3: int8 path. x per-row symmetric int8 quant, W = int4 values exact in
// int8, main GEMM via mfma_i32_16x16x64_i8 (2x K/instr vs bf16). LoRA done
// exactly-enough: xA = x_i8 @ A_i8 (tiny MFMA kernel), added in the GEMM
// epilogue with one bf16 MFMA round (K=16 zero-padded), bias preloaded in C.

static constexpr int Mdim = 8192;
static constexpr int Ndim = 4096;
static constexpr int Kdim = 4096;

typedef __bf16 bf16x8 __attribute__((ext_vector_type(8)));
typedef float f32x4 __attribute__((ext_vector_type(4)));
typedef int   i32x4 __attribute__((ext_vector_type(4)));

__device__ __forceinline__ void async_copy16(const void* gptr, void* lptr) {
    auto g = (const __attribute__((address_space(1))) unsigned char*)(uintptr_t)gptr;
    auto l = (__attribute__((address_space(3))) unsigned char*)(uintptr_t)lptr;
    __builtin_amdgcn_global_load_lds(g, l, 16, 0, 0);
}

// ---------------- prep: 4 roles by blockIdx ----------------
// role A (1 blk): quantize lora_A -> a_i8t[16][K] (transposed), per-tensor scale
// role W (4096):  qweight int32 -> int8 [N][K]
// role X (8192):  per-row int8 quant of x + row_scale
// role Bt (16):   lora_B [16][N] -> bf16 Blbt[N][16] (transposed)
static constexpr int BLK_W = Ndim * Kdim / (256 * 16);  // 4096
static constexpr int BLK_X = Mdim;                      // 8192
static constexpr int BLK_BT = Ndim / 256;               // 16

__global__ void __launch_bounds__(256) prep_kernel(
        const float* __restrict__ x,
        const int* __restrict__ qw,
        const float* __restrict__ lA,   // [K][16]
        const float* __restrict__ lB,   // [16][N]
        int8_t* __restrict__ x_i8,      // [M][K]
        int8_t* __restrict__ w_i8,      // [N][K]
        int8_t* __restrict__ a_i8t,     // [16][K]
        __bf16* __restrict__ Blbt,      // [N][16]
        float* __restrict__ row_scale,  // [M]
        float* __restrict__ a_scale_g) {
    __shared__ float red[8];
    int b = blockIdx.x;
    const int tid = threadIdx.x;

    if (b == 0) {
        // ---- role A ----
        float am = 0.f;
        const float4* ap = (const float4*)lA + tid * 64;  // 256 floats/thread
        for (int i = 0; i < 64; ++i) {
            float4 v = ap[i];
            am = fmaxf(am, fmaxf(fmaxf(fabsf(v.x), fabsf(v.y)),
                                 fmaxf(fabsf(v.z), fabsf(v.w))));
        }
        for (int off = 32; off; off >>= 1) am = fmaxf(am, __shfl_xor(am, off));
        if ((tid & 63) == 0) red[tid >> 6] = am;
        __syncthreads();
        if (tid == 0) {
            float m = fmaxf(fmaxf(red[0], red[1]), fmaxf(red[2], red[3]));
            red[4] = m;
            a_scale_g[0] = m > 0.f ? m / 127.f : 0.f;
        }
        __syncthreads();
        float amax = red[4];
        float inv = amax > 0.f ? 127.f / amax : 0.f;
        int k0 = tid * 16;
#pragma unroll
        for (int r = 0; r < 16; ++r) {
            int8_t o[16];
#pragma unroll
            for (int kk = 0; kk < 16; ++kk) {
                float v = lA[(size_t)(k0 + kk) * 16 + r];
                o[kk] = (int8_t)(int)rintf(v * inv);
            }
            *(i32x4*)(a_i8t + (size_t)r * Kdim + k0) = *(i32x4*)o;
        }
        return;
    }
    b -= 1;

    if (b < BLK_W) {
        // ---- role W ----
        size_t idx = ((size_t)b * 256 + tid) * 16;
        const int4* q = (const int4*)(qw + idx);
        int4 q0 = q[0], q1 = q[1], q2 = q[2], q3 = q[3];
        int8_t o[16] = {(int8_t)q0.x, (int8_t)q0.y, (int8_t)q0.z, (int8_t)q0.w,
                        (int8_t)q1.x, (int8_t)q1.y, (int8_t)q1.z, (int8_t)q1.w,
                        (int8_t)q2.x, (int8_t)q2.y, (int8_t)q2.z, (int8_t)q2.w,
                        (int8_t)q3.x, (int8_t)q3.y, (int8_t)q3.z, (int8_t)q3.w};
        *(i32x4*)(w_i8 + idx) = *(i32x4*)o;
        return;
    }
    b -= BLK_W;

    if (b < BLK_X) {
        // ---- role X: one block per row ----
        const int row = b;
        const float4* xp = (const float4*)(x + (size_t)row * Kdim) + tid * 4;
        float4 v0 = xp[0], v1 = xp[1], v2 = xp[2], v3 = xp[3];
        float am = 0.f;
        am = fmaxf(am, fmaxf(fmaxf(fabsf(v0.x), fabsf(v0.y)), fmaxf(fabsf(v0.z), fabsf(v0.w))));
        am = fmaxf(am, fmaxf(fmaxf(fabsf(v1.x), fabsf(v1.y)), fmaxf(fabsf(v1.z), fabsf(v1.w))));
        am = fmaxf(am, fmaxf(fmaxf(fabsf(v2.x), fabsf(v2.y)), fmaxf(fabsf(v2.z), fabsf(v2.w))));
        am = fmaxf(am, fmaxf(fmaxf(fabsf(v3.x), fabsf(v3.y)), fmaxf(fabsf(v3.z), fabsf(v3.w))));
        for (int off = 32; off; off >>= 1) am = fmaxf(am, __shfl_xor(am, off));
        if ((tid & 63) == 0) red[tid >> 6] = am;
        __syncthreads();
        if (tid == 0) {
            float m = fmaxf(fmaxf(red[0], red[1]), fmaxf(red[2], red[3]));
            red[4] = m;
            row_scale[row] = m > 0.f ? m / 127.f : 0.f;
        }
        __syncthreads();
        float amax = red[4];
        float inv = amax > 0.f ? 127.f / amax : 0.f;
        float vv[16] = {v0.x, v0.y, v0.z, v0.w, v1.x, v1.y, v1.z, v1.w,
                        v2.x, v2.y, v2.z, v2.w, v3.x, v3.y, v3.z, v3.w};
        int8_t o[16];
#pragma unroll
        for (int i = 0; i < 16; ++i) o[i] = (int8_t)(int)rintf(vv[i] * inv);
        *(i32x4*)(x_i8 + (size_t)row * Kdim + tid * 16) = *(i32x4*)o;
        return;
    }
    b -= BLK_X;

    {
        // ---- role Bt ----
        int c = b * 256 + tid;
        __bf16 tmp[16];
#pragma unroll
        for (int r = 0; r < 16; ++r) tmp[r] = (__bf16)lB[(size_t)r * Ndim + c];
        *(bf16x8*)(Blbt + (size_t)c * 16) = *(bf16x8*)tmp;
        *(bf16x8*)(Blbt + (size_t)c * 16 + 8) = *(bf16x8*)(tmp + 8);
    }
}

// ---------------- xA = x_i8 @ A_i8^T, dequant -> bf16 [M][16] ----------------
// 128 blocks x 64 rows; wave w handles rows w*16..w*16+15 (one 16x16 tile).
__global__ void __launch_bounds__(256) xa_kernel(
        const int8_t* __restrict__ x_i8,
        const int8_t* __restrict__ a_i8t,
        const float* __restrict__ row_scale,
        const float* __restrict__ a_scale_g,
        __bf16* __restrict__ xab) {
    __shared__ __align__(16) char sX[64 * 64];
    __shared__ __align__(16) char sAq[16 * 64];
    const int tid = threadIdx.x, wave = tid >> 6, lane = tid & 63;
    const int quad = lane >> 4, l16 = lane & 15;
    const int bm = blockIdx.x;
    const size_t xbase = ((size_t)bm * 64 + (tid >> 2)) * Kdim + (tid & 3) * 16;
    i32x4 acc = {0, 0, 0, 0};
    for (int k0 = 0; k0 < Kdim; k0 += 64) {
        __syncthreads();
        async_copy16(x_i8 + xbase + k0, sX + tid * 16);
        if (tid < 64)
            async_copy16(a_i8t + (size_t)(tid >> 2) * Kdim + (tid & 3) * 16 + k0,
                         sAq + tid * 16);
        __syncthreads();
        i32x4 af = *(const i32x4*)(sX + (wave * 16 + l16) * 64 + quad * 16);
        i32x4 bf = *(const i32x4*)(sAq + l16 * 64 + quad * 16);
        acc = __builtin_amdgcn_mfma_i32_16x16x64_i8(af, bf, acc, 0, 0, 0);
    }
    const float asc = a_scale_g[0];
    const int rl = wave * 16 + quad * 4;
#pragma unroll
    for (int r = 0; r < 4; ++r) {
        int grow = bm * 64 + rl + r;
        float v = (float)acc[r] * row_scale[grow] * asc;
        xab[(size_t)grow * 16 + l16] = (__bf16)v;
    }
}

// ---------------- main GEMM (int8) + fused epilogue ----------------
__global__ void __launch_bounds__(256) gemm_kernel(
        const int8_t* __restrict__ Xq,     // [M][K]
        const int8_t* __restrict__ Wq,     // [N][K]
        const float* __restrict__ scales,  // [1] weight scale
        const float* __restrict__ bias,    // [N]
        const float* __restrict__ row_scale, // [M]
        const __bf16* __restrict__ xab,    // [M][16]
        const __bf16* __restrict__ Blbt,   // [N][16]
        float* __restrict__ out) {         // [M][N]
    __shared__ __align__(16) char smem[16384 + 512];
    char* sA = smem;
    char* sB = smem + 8192;

    const int tid = threadIdx.x, wave = tid >> 6, lane = tid & 63;
    const int wm = wave >> 1, wn = wave & 1;
    const int quad = lane >> 4, l16 = lane & 15;
    const int bm = blockIdx.y, bn = blockIdx.x;

    const int arow = tid >> 2;
    const int acolb = (tid & 3) * 16;
    const size_t a_base = (size_t)(bm * 128 + arow) * Kdim + acolb;
    const size_t b_base = (size_t)(bn * 128 + arow) * Kdim + acolb;

    i32x4 acc[4][4];
#pragma unroll
    for (int i = 0; i < 4; ++i)
#pragma unroll
        for (int j = 0; j < 4; ++j) acc[i][j] = i32x4{0, 0, 0, 0};

    for (int k0 = 0; k0 < Kdim; k0 += 64) {
        __syncthreads();
        async_copy16(Xq + a_base + k0,                     sA + tid * 16);
        async_copy16(Xq + a_base + (size_t)64 * Kdim + k0, sA + 4096 + tid * 16);
        async_copy16(Wq + b_base + k0,                     sB + tid * 16);
        async_copy16(Wq + b_base + (size_t)64 * Kdim + k0, sB + 4096 + tid * 16);
        __syncthreads();

        i32x4 aF[4], bF[4];
#pragma unroll
        for (int i = 0; i < 4; ++i)
            aF[i] = *(const i32x4*)(sA + (wm * 64 + i * 16 + l16) * 64 + quad * 16);
#pragma unroll
        for (int j = 0; j < 4; ++j)
            bF[j] = *(const i32x4*)(sB + (wn * 64 + j * 16 + l16) * 64 + quad * 16);

#pragma unroll
        for (int i = 0; i < 4; ++i)
#pragma unroll
            for (int j = 0; j < 4; ++j)
                acc[i][j] = __builtin_amdgcn_mfma_i32_16x16x64_i8(aF[i], bF[j], acc[i][j], 0, 0, 0);
    }

    // -------- epilogue: lora (bf16 MFMA, K=16 zero-padded) + bias + dequant --------
    const float wsc = scales[0];
    float bj4[4];
#pragma unroll
    for (int j = 0; j < 4; ++j) bj4[j] = bias[bn * 128 + wn * 64 + j * 16 + l16];

    __syncthreads();  // all waves done with sA/sB
    async_copy16((const char*)(xab + (size_t)bm * 128 * 16) + tid * 16, smem + tid * 16);
    async_copy16((const char*)(Blbt + (size_t)bn * 128 * 16) + tid * 16, smem + 4096 + tid * 16);
    if (tid < 32)
        async_copy16((const char*)(row_scale + bm * 128) + tid * 16, smem + 8192 + tid * 16);
    __syncthreads();

    const __bf16* sXA = (const __bf16*)smem;          // [128][16]
    const __bf16* sBL = (const __bf16*)(smem + 4096); // [128 cols][16]
    const float*  sRS = (const float*)(smem + 8192);  // [128]

    bf16x8 zf;
#pragma unroll
    for (int k = 0; k < 8; ++k) zf[k] = (__bf16)0.f;

    bf16x8 aF2[4], bF2[4];
#pragma unroll
    for (int i = 0; i < 4; ++i) {
        if (quad < 2) aF2[i] = *(const bf16x8*)(sXA + (wm * 64 + i * 16 + l16) * 16 + quad * 8);
        else          aF2[i] = zf;
    }
#pragma unroll
    for (int j = 0; j < 4; ++j) {
        if (quad < 2) bF2[j] = *(const bf16x8*)(sBL + (wn * 64 + j * 16 + l16) * 16 + quad * 8);
        else          bF2[j] = zf;
    }

    f32x4 lacc[4][4];
#pragma unroll
    for (int j = 0; j < 4; ++j)
#pragma unroll
        for (int i = 0; i < 4; ++i)
            lacc[i][j] = f32x4{bj4[j], bj4[j], bj4[j], bj4[j]};

#pragma unroll
    for (int i = 0; i < 4; ++i)
#pragma unroll
        for (int j = 0; j < 4; ++j)
            lacc[i][j] = __builtin_amdgcn_mfma_f32_16x16x32_bf16(aF2[i], bF2[j], lacc[i][j], 0, 0, 0);

    const int col0 = bn * 128 + wn * 64 + l16;
    const int rl0 = wm * 64 + quad * 4;
#pragma unroll
    for (int j = 0; j < 4; ++j) {
        const int col = col0 + j * 16;
#pragma unroll
        for (int i = 0; i < 4; ++i) {
            const int lr = rl0 + i * 16;
#pragma unroll
            for (int r = 0; r < 4; ++r) {
                float sx = sRS[lr + r] * wsc;
                out[(size_t)(bm * 128 + lr + r) * Ndim + col] =
                    (float)acc[i][j][r] * sx + lacc[i][j][r];
            }
        }
    }
}

extern "C" void kernel_launch(void* const* d_in, const int* in_sizes, int n_in,
                              void* d_out, int out_size, void* d_ws, size_t ws_size,
                              hipStream_t stream) {
    const float* x      = (const float*)d_in[0];
    const int*   qw     = (const int*)d_in[1];
    const float* scales = (const float*)d_in[2];
    const float* bias   = (const float*)d_in[3];
    const float* lA     = (const float*)d_in[4];
    const float* lB     = (const float*)d_in[5];
    float* out = (float*)d_out;

    char* ws = (char*)d_ws;
    int8_t* x_i8   = (int8_t*)ws;                               // 33.55 MB
    int8_t* w_i8   = (int8_t*)(ws + 33554432);                  // 16.78 MB
    int8_t* a_i8t  = (int8_t*)(ws + 50331648);                  // 64 KB
    __bf16* xab    = (__bf16*)(ws + 50397184);                  // 256 KB
    __bf16* Blbt   = (__bf16*)(ws + 50659328);                  // 128 KB
    float* row_scale = (float*)(ws + 50790400);                 // 32 KB
    float* a_scale_g = (float*)(ws + 50823168);                 // 4 B

    const int prep_blocks = 1 + BLK_W + BLK_X + BLK_BT;         // 12305
    prep_kernel<<<prep_blocks, 256, 0, stream>>>(
        x, qw, lA, lB, x_i8, w_i8, a_i8t, Blbt, row_scale, a_scale_g);
    xa_kernel<<<Mdim / 64, 256, 0, stream>>>(x_i8, a_i8t, row_scale, a_scale_g, xab);
    dim3 grid(Ndim / 128, Mdim / 128);
    gemm_kernel<<<grid, 256, 0, stream>>>(x_i8, w_i8, scales, bias, row_scale,
                                          xab, Blbt, out);
}